// Round 8
// baseline (1412.435 us; speedup 1.0000x reference)
//
#include <hip/hip_runtime.h>
#include <hip/hip_bf16.h>
#include <math.h>

#define NN 50000
#define NE 1600000
#define D 64
#define DE 32
#define H 4
#define DH 16
#define L 3

typedef __attribute__((ext_vector_type(8))) short bf16x8;
typedef __attribute__((ext_vector_type(4))) float f32x4;

__device__ __forceinline__ short f2b(float f) {
    __hip_bfloat16 h = __float2bfloat16(f);
    short s;
    __builtin_memcpy(&s, &h, 2);
    return s;
}
__device__ __forceinline__ float b2f(unsigned short u) {
    unsigned int x = ((unsigned int)u) << 16;
    float f; __builtin_memcpy(&f, &x, 4); return f;
}
__device__ __forceinline__ float b2f_lo(unsigned int p) {
    unsigned int x = p << 16;
    float f; __builtin_memcpy(&f, &x, 4); return f;
}
__device__ __forceinline__ float b2f_hi(unsigned int p) {
    unsigned int x = p & 0xffff0000u;
    float f; __builtin_memcpy(&f, &x, 4); return f;
}

// ======================= CSR build (per launch) =======================

__global__ void deg_kernel(const int* __restrict__ dst, int* __restrict__ cnt) {
    int e = blockIdx.x * 256 + threadIdx.x;
    if (e >= NE) return;
    atomicAdd(&cnt[dst[e]], 1);
}

__global__ void block_sum_kernel(const int* __restrict__ cnt, int* __restrict__ bsum) {
    int b = blockIdx.x, t = threadIdx.x;
    int base = b * 1024 + t * 4;
    int s = 0;
#pragma unroll
    for (int i = 0; i < 4; i++) { int idx = base + i; if (idx < NN) s += cnt[idx]; }
#pragma unroll
    for (int off = 32; off; off >>= 1) s += __shfl_down(s, off);
    __shared__ int wsum[4];
    if ((t & 63) == 0) wsum[t >> 6] = s;
    __syncthreads();
    if (t == 0) bsum[b] = wsum[0] + wsum[1] + wsum[2] + wsum[3];
}

__global__ void scan_bsum_kernel(int* __restrict__ bsum, int nb) {
    if (blockIdx.x == 0 && threadIdx.x == 0) {
        int run = 0;
        for (int i = 0; i < nb; i++) { int c = bsum[i]; bsum[i] = run; run += c; }
    }
}

__global__ void scan_block_kernel(const int* __restrict__ cnt, const int* __restrict__ bsum,
                                  int* __restrict__ offsets) {
    int b = blockIdx.x, t = threadIdx.x;
    int base = b * 1024 + t * 4;
    int v[4]; int s = 0;
#pragma unroll
    for (int i = 0; i < 4; i++) { int idx = base + i; v[i] = (idx < NN) ? cnt[idx] : 0; s += v[i]; }
    int lane = t & 63, w = t >> 6;
    int x = s;
#pragma unroll
    for (int off = 1; off < 64; off <<= 1) {
        int y = __shfl_up(x, off);
        if (lane >= off) x += y;
    }
    __shared__ int wsum[4];
    if (lane == 63) wsum[w] = x;
    __syncthreads();
    int woff = 0;
    for (int i = 0; i < w; i++) woff += wsum[i];
    int run = bsum[b] + woff + x - s;
#pragma unroll
    for (int i = 0; i < 4; i++) {
        int idx = base + i;
        if (idx < NN) offsets[idx] = run;
        run += v[i];
    }
}

__global__ void scatter_kernel(const int* __restrict__ src, const int* __restrict__ dst,
                               const int* __restrict__ offsets,
                               int* __restrict__ cursor,
                               int* __restrict__ sorted_eid,
                               int* __restrict__ sorted_src,
                               int* __restrict__ sorted_dst) {
    int e = blockIdx.x * 256 + threadIdx.x;
    if (e >= NE) return;
    int d0 = dst[e];
    int pos = atomicAdd(&cursor[d0], 1);
    int position = offsets[d0] + pos;
    sorted_eid[position] = e;
    sorted_src[position] = src[e];
    sorted_dst[position] = d0;
}

// ---- fused: permute fp32 e -> dst-sorted bf16 eb_s AND layer-0 edge bias ----
// 4 threads per edge, 8 cols each. Grid exact: NE*4/256 = 25000 blocks.
__global__ void eprep_kernel(const float* __restrict__ e32, const int* __restrict__ sorted_eid,
                             const float* __restrict__ We,      // layer-0 [32][4]
                             unsigned short* __restrict__ eb_s,
                             float* __restrict__ ebias_s) {
    int t = blockIdx.x * 256 + threadIdx.x;
    int p = t >> 2;
    int g = t & 3;
    int eid = sorted_eid[p];
    const float* ep = e32 + (size_t)eid * DE + g * 8;
    float4 x0 = *(const float4*)(ep);
    float4 x1 = *(const float4*)(ep + 4);
    float y[8] = {x0.x, x0.y, x0.z, x0.w, x1.x, x1.y, x1.z, x1.w};
    bf16x8 ob;
#pragma unroll
    for (int j = 0; j < 8; j++) ob[j] = f2b(y[j]);
    *(bf16x8*)(eb_s + (size_t)p * DE + g * 8) = ob;
    float p0 = 0.f, p1 = 0.f, p2 = 0.f, p3 = 0.f;
#pragma unroll
    for (int j = 0; j < 8; j++) {
        float4 w = *(const float4*)(We + (g * 8 + j) * 4);
        p0 += y[j] * w.x; p1 += y[j] * w.y; p2 += y[j] * w.z; p3 += y[j] * w.w;
    }
#pragma unroll
    for (int off = 1; off < 4; off <<= 1) {
        p0 += __shfl_xor(p0, off, 4);
        p1 += __shfl_xor(p1, off, 4);
        p2 += __shfl_xor(p2, off, 4);
        p3 += __shfl_xor(p3, off, 4);
    }
    float bsel = (g == 0) ? p0 : (g == 1) ? p1 : (g == 2) ? p2 : p3;
    ebias_s[p * H + g] = bsel;
}

// ---- Wem[L][160][32] fp32 -> Wt[L][32][160] bf16 (transposed) ----
__global__ void wconv_kernel(const float* __restrict__ Wem, unsigned short* __restrict__ Wt) {
    int t = blockIdx.x * 256 + threadIdx.x;
    if (t >= L * 32 * 160) return;
    int l = t / 5120;
    int r = t % 5120;
    int n = r / 160;
    int k = r % 160;
    Wt[t] = (unsigned short)f2b(Wem[l * 5120 + k * 32 + n]);
}

// ---- h = node_features (fp32) + hb = bf16(node_features) ----
__global__ void hconv_kernel(const float* __restrict__ nf, float* __restrict__ h,
                             unsigned short* __restrict__ hb) {
    int t = blockIdx.x * 256 + threadIdx.x;
    if (t >= NN * D) return;
    float x = nf[t];
    h[t] = x;
    hb[t] = (unsigned short)f2b(x);
}

// ======================= per-layer kernels =======================

// ---- q = (h@Wq)*0.25 ; kv = pack(bf16(k), bf16(v)) ; 16 nodes/block ----
__global__ void qkv_kernel(const float* __restrict__ h,
                           const float* __restrict__ Wq,
                           const float* __restrict__ Wk,
                           const float* __restrict__ Wv,
                           float* __restrict__ q, unsigned int* __restrict__ kv) {
    __shared__ float sW[3 * 4096];   // 48 KB
    __shared__ float sh[16][D];
    int col = threadIdx.x;           // 0..63
    int wv = threadIdx.y;            // 0..3
    int tid = wv * 64 + col;
    int base = blockIdx.x * 16;
    for (int i = tid; i < 4096; i += 256) {
        sW[i] = Wq[i]; sW[4096 + i] = Wk[i]; sW[8192 + i] = Wv[i];
    }
    for (int i = tid; i < 16 * D; i += 256) {
        int n = base + (i >> 6);
        sh[i >> 6][i & 63] = h[n * D + (i & 63)];
    }
    __syncthreads();
#pragma unroll
    for (int it = 0; it < 4; it++) {
        int ln = wv * 4 + it;
        int node = base + ln;
        float aq = 0.f, ak = 0.f, av = 0.f;
#pragma unroll
        for (int kk = 0; kk < D; kk++) {
            float hv = sh[ln][kk];
            aq += hv * sW[kk * D + col];
            ak += hv * sW[4096 + kk * D + col];
            av += hv * sW[8192 + kk * D + col];
        }
        q[node * D + col] = aq * 0.25f;
        unsigned int kb = (unsigned int)(unsigned short)f2b(ak);
        unsigned int vb = (unsigned int)(unsigned short)f2b(av);
        kv[node * D + col] = (vb << 16) | kb;
    }
}

// ---- fused per-dst-node online-softmax attention + aggregation (8-wide) ----
__global__ void attn_kernel(const float* __restrict__ q, const unsigned int* __restrict__ kv,
                            const float* __restrict__ ebias_s,
                            const int* __restrict__ sorted_src,
                            const int* __restrict__ offsets,
                            float* __restrict__ agg) {
    int node = blockIdx.x * 4 + threadIdx.y;
    node = __builtin_amdgcn_readfirstlane(node);
    if (node >= NN) return;
    int lane = threadIdx.x;
    int hh = lane >> 4;
    float qv = q[node * D + lane];
    int beg = offsets[node];
    int end = (node == NN - 1) ? NE : offsets[node + 1];
    float mmax = -INFINITY, den = 0.f, acc = 0.f;
    int i = beg;
    for (; i + 8 <= end; i += 8) {
        int ss[8]; unsigned int kk8[8]; float bb8[8], dd[8];
#pragma unroll
        for (int u = 0; u < 8; u++) ss[u] = sorted_src[i + u];
#pragma unroll
        for (int u = 0; u < 8; u++) kk8[u] = kv[ss[u] * D + lane];
#pragma unroll
        for (int u = 0; u < 8; u++) bb8[u] = ebias_s[(i + u) * H + hh];
#pragma unroll
        for (int u = 0; u < 8; u++) dd[u] = qv * b2f_lo(kk8[u]);
#pragma unroll
        for (int off = 1; off < 16; off <<= 1) {
#pragma unroll
            for (int u = 0; u < 8; u++) dd[u] += __shfl_xor(dd[u], off, 16);
        }
        float nm = mmax;
#pragma unroll
        for (int u = 0; u < 8; u++) { dd[u] += bb8[u]; nm = fmaxf(nm, dd[u]); }
        float scale = __expf(mmax - nm);
        float ps = 0.f, av = 0.f;
#pragma unroll
        for (int u = 0; u < 8; u++) {
            float p = __expf(dd[u] - nm);
            ps += p;
            av += p * b2f_hi(kk8[u]);
        }
        den = den * scale + ps;
        acc = acc * scale + av;
        mmax = nm;
    }
    for (; i < end; i++) {
        int s = sorted_src[i];
        unsigned int kvv = kv[s * D + lane];
        float b = ebias_s[i * H + hh];
        float dot = qv * b2f_lo(kvv);
#pragma unroll
        for (int off = 1; off < 16; off <<= 1) dot += __shfl_xor(dot, off, 16);
        float score = dot + b;
        float nm = fmaxf(mmax, score);
        float scale = __expf(mmax - nm);
        float p = __expf(score - nm);
        den = den * scale + p;
        acc = acc * scale + p * b2f_hi(kvv);
        mmax = nm;
    }
    agg[node * D + lane] = acc / (den + 1e-9f);
}

// ---- h = LN(h + agg @ Wo) + bf16 shadow ; 16 nodes/block ----
__global__ void node_update_kernel(float* __restrict__ h, const float* __restrict__ agg,
                                   const float* __restrict__ Wo,
                                   const float* __restrict__ gn,
                                   const float* __restrict__ bn,
                                   unsigned short* __restrict__ hb) {
    __shared__ float sWo[4096];      // 16 KB
    __shared__ float sagg[16][D];
    int col = threadIdx.x, wv = threadIdx.y;
    int tid = wv * 64 + col;
    int base = blockIdx.x * 16;
    for (int i = tid; i < 4096; i += 256) sWo[i] = Wo[i];
    for (int i = tid; i < 16 * D; i += 256) {
        int n = base + (i >> 6);
        sagg[i >> 6][i & 63] = agg[n * D + (i & 63)];
    }
    __syncthreads();
    float gcol = gn[col], bcol = bn[col];
#pragma unroll
    for (int it = 0; it < 4; it++) {
        int ln = wv * 4 + it;
        int node = base + ln;
        float acc = 0.f;
#pragma unroll
        for (int kk = 0; kk < D; kk++) acc += sagg[ln][kk] * sWo[kk * D + col];
        float x = h[node * D + col] + acc;
        float sum = x, sq = x * x;
#pragma unroll
        for (int off = 32; off; off >>= 1) {
            sum += __shfl_xor(sum, off);
            sq += __shfl_xor(sq, off);
        }
        float mu = sum * (1.f / 64.f);
        float var = sq * (1.f / 64.f) - mu * mu;
        float out = (x - mu) * rsqrtf(var + 1e-5f) * gcol + bcol;
        h[node * D + col] = out;
        hb[node * D + col] = (unsigned short)f2b(out);
    }
}

// ---- e = LN(e + gelu([h[src]|h[dst]|e] @ Wem + bem)) via bf16 MFMA.
// Epilogue transposes C through LDS so each lane owns 8 contiguous cols of one
// edge: width-4 reductions (12 shuffles/wave vs 96), coalesced 16B stores.
// Always computes next-layer ebias (only launched for layers 0..L-2).
__global__ void edge_update_mfma_kernel(const unsigned short* __restrict__ hb,
                                        unsigned short* __restrict__ eb_s,
                                        const int* __restrict__ sorted_src,
                                        const int* __restrict__ sorted_dst,
                                        const unsigned short* __restrict__ Wt,   // [32][160] bf16
                                        const float* __restrict__ bem,
                                        const float* __restrict__ ge,
                                        const float* __restrict__ be,
                                        const float* __restrict__ We_next,       // [32][4]
                                        float* __restrict__ ebias_s) {
    __shared__ float xpose[4][16 * 36];          // per-wave 16 rows x 36 (pad), 9 KB
    int wave = threadIdx.x >> 6;
    int lane = threadIdx.x & 63;
    int we = blockIdx.x * 64 + wave * 16;        // first sorted position of this wave
    int m = lane & 15;
    int quad = lane >> 4;
    int p_m = we + m;
    int s_idx = sorted_src[p_m], d_idx = sorted_dst[p_m];

    const unsigned short* as = hb + (size_t)s_idx * D + quad * 8;
    const unsigned short* ad = hb + (size_t)d_idx * D + quad * 8;
    const unsigned short* w0 = Wt + m * 160 + quad * 8;

    f32x4 c0 = {0.f, 0.f, 0.f, 0.f};
    f32x4 c1 = {0.f, 0.f, 0.f, 0.f};

#pragma unroll
    for (int ks = 0; ks < 4; ks++) {
        const unsigned short* ap = (ks < 2) ? as : ad;
        bf16x8 a = *(const bf16x8*)(ap + (ks & 1) * 32);
        bf16x8 b0 = *(const bf16x8*)(w0 + ks * 32);
        bf16x8 b1 = *(const bf16x8*)(w0 + ks * 32 + 16 * 160);
        c0 = __builtin_amdgcn_mfma_f32_16x16x32_bf16(a, b0, c0, 0, 0, 0);
        c1 = __builtin_amdgcn_mfma_f32_16x16x32_bf16(a, b1, c1, 0, 0, 0);
    }
    {
        bf16x8 a = *(const bf16x8*)(eb_s + (size_t)p_m * DE + quad * 8);
        bf16x8 b0 = *(const bf16x8*)(w0 + 4 * 32);
        bf16x8 b1 = *(const bf16x8*)(w0 + 4 * 32 + 16 * 160);
        c0 = __builtin_amdgcn_mfma_f32_16x16x32_bf16(a, b0, c0, 0, 0, 0);
        c1 = __builtin_amdgcn_mfma_f32_16x16x32_bf16(a, b1, c1, 0, 0, 0);
    }

    // transpose C into LDS: value (row=quad*4+reg, col=m / m+16)
    float* xp = &xpose[wave][0];
#pragma unroll
    for (int reg = 0; reg < 4; reg++) {
        int row = quad * 4 + reg;
        xp[row * 36 + m] = c0[reg];
        xp[row * 36 + m + 16] = c1[reg];
    }
    __syncthreads();

    // each lane: edge er = lane>>2, col group g = lane&3 (cols g*8..g*8+7)
    int er = lane >> 2;
    int g = lane & 3;
    int ep = we + er;                            // sorted position
    const float* xr = xp + er * 36 + g * 8;
    float4 ya = *(const float4*)(xr);
    float4 yb = *(const float4*)(xr + 4);
    float y[8] = {ya.x, ya.y, ya.z, ya.w, yb.x, yb.y, yb.z, yb.w};
    float4 bm0 = *(const float4*)(bem + g * 8);
    float4 bm1 = *(const float4*)(bem + g * 8 + 4);
    float bm[8] = {bm0.x, bm0.y, bm0.z, bm0.w, bm1.x, bm1.y, bm1.z, bm1.w};
    bf16x8 eo = *(const bf16x8*)(eb_s + (size_t)ep * DE + g * 8);
    float s = 0.f, sq = 0.f;
#pragma unroll
    for (int j = 0; j < 8; j++) {
        float v = y[j] + bm[j];
        float u = 1.5957691216057308f * (v + 0.044715f * v * v * v);
        float t = 1.f - 2.f / (1.f + __expf(u));
        v = 0.5f * v * (1.f + t);
        v += b2f((unsigned short)eo[j]);
        y[j] = v;
        s += v;
        sq += v * v;
    }
#pragma unroll
    for (int off = 1; off < 4; off <<= 1) {
        s += __shfl_xor(s, off, 4);
        sq += __shfl_xor(sq, off, 4);
    }
    float mu = s * (1.f / 32.f);
    float var = sq * (1.f / 32.f) - mu * mu;
    float inv = rsqrtf(var + 1e-5f);
    float4 g0 = *(const float4*)(ge + g * 8);
    float4 g1 = *(const float4*)(ge + g * 8 + 4);
    float4 b0 = *(const float4*)(be + g * 8);
    float4 b1 = *(const float4*)(be + g * 8 + 4);
    float gg[8] = {g0.x, g0.y, g0.z, g0.w, g1.x, g1.y, g1.z, g1.w};
    float bb[8] = {b0.x, b0.y, b0.z, b0.w, b1.x, b1.y, b1.z, b1.w};
    bf16x8 zb;
    float z[8];
#pragma unroll
    for (int j = 0; j < 8; j++) {
        z[j] = (y[j] - mu) * inv * gg[j] + bb[j];
        zb[j] = f2b(z[j]);
    }
    *(bf16x8*)(eb_s + (size_t)ep * DE + g * 8) = zb;
    // next-layer edge bias
    float p0 = 0.f, p1 = 0.f, p2 = 0.f, p3 = 0.f;
#pragma unroll
    for (int j = 0; j < 8; j++) {
        float4 w = *(const float4*)(We_next + (g * 8 + j) * 4);
        p0 += z[j] * w.x; p1 += z[j] * w.y; p2 += z[j] * w.z; p3 += z[j] * w.w;
    }
#pragma unroll
    for (int off = 1; off < 4; off <<= 1) {
        p0 += __shfl_xor(p0, off, 4);
        p1 += __shfl_xor(p1, off, 4);
        p2 += __shfl_xor(p2, off, 4);
        p3 += __shfl_xor(p3, off, 4);
    }
    float bsel = (g == 0) ? p0 : (g == 1) ? p1 : (g == 2) ? p2 : p3;
    ebias_s[ep * H + g] = bsel;
}

extern "C" void kernel_launch(void* const* d_in, const int* in_sizes, int n_in,
                              void* d_out, int out_size, void* d_ws, size_t ws_size,
                              hipStream_t stream) {
    const float* node_features = (const float*)d_in[0];
    const float* e = (const float*)d_in[1];   // pristine fp32 e (read-only)
    const int* edge_index = (const int*)d_in[2];
    const int* src = edge_index;
    const int* dst = edge_index + NE;
    const float* Wq = (const float*)d_in[3];
    const float* Wk = (const float*)d_in[4];
    const float* Wv = (const float*)d_in[5];
    const float* Wo = (const float*)d_in[6];
    const float* We = (const float*)d_in[7];
    const float* Wem = (const float*)d_in[8];
    const float* bem = (const float*)d_in[9];
    const float* gn = (const float*)d_in[10];
    const float* bn = (const float*)d_in[11];
    const float* ge = (const float*)d_in[12];
    const float* be = (const float*)d_in[13];

    float* h = (float*)d_out;       // h lives in d_out

    float* ws = (float*)d_ws;
    float* q = ws;                                       // N*D f32
    unsigned int* kv = (unsigned int*)(q + NN * D);      // N*D u32 (packed bf16 k|v)
    float* agg = (float*)(kv + NN * D);                  // N*D f32
    float* ebias_s = agg + NN * D;                       // E*H f32 (sorted order)
    int* offsets = (int*)(ebias_s + (size_t)NE * H);     // NN
    int* cursor = offsets + NN;                          // NN
    int* bsum = cursor + NN;                             // 64
    int* sorted_eid = bsum + 64;                         // NE
    int* sorted_src = sorted_eid + NE;                   // NE
    int* sorted_dst = sorted_src + NE;                   // NE
    unsigned short* Wt = (unsigned short*)(sorted_dst + NE);  // L*32*160 bf16
    unsigned short* hb = Wt + L * 32 * 160;              // N*D bf16
    unsigned short* eb_s = hb + NN * D;                  // E*DE bf16 e-state (sorted)

    const int NB = (NN + 1023) / 1024;

    // ---- CSR build + preconverts (inputs constant; rebuilt every launch) ----
    hipMemsetAsync(cursor, 0, NN * sizeof(int), stream);
    deg_kernel<<<(NE + 255) / 256, 256, 0, stream>>>(dst, cursor);
    block_sum_kernel<<<NB, 256, 0, stream>>>(cursor, bsum);
    scan_bsum_kernel<<<1, 64, 0, stream>>>(bsum, NB);
    scan_block_kernel<<<NB, 256, 0, stream>>>(cursor, bsum, offsets);
    hipMemsetAsync(cursor, 0, NN * sizeof(int), stream);
    scatter_kernel<<<(NE + 255) / 256, 256, 0, stream>>>(src, dst, offsets, cursor,
                                                         sorted_eid, sorted_src, sorted_dst);
    wconv_kernel<<<(L * 32 * 160 + 255) / 256, 256, 0, stream>>>(Wem, Wt);
    hconv_kernel<<<(NN * D + 255) / 256, 256, 0, stream>>>(node_features, h, hb);
    // fused: sorted bf16 e-state + layer-0 edge bias (one pass over e)
    eprep_kernel<<<NE * 4 / 256, 256, 0, stream>>>(e, sorted_eid, We, eb_s, ebias_s);

    for (int layer = 0; layer < L; layer++) {
        const float* Wq_l = Wq + layer * D * D;
        const float* Wk_l = Wk + layer * D * D;
        const float* Wv_l = Wv + layer * D * D;
        const float* Wo_l = Wo + layer * D * D;
        const unsigned short* Wt_l = Wt + layer * 32 * 160;
        const float* bem_l = bem + layer * DE;
        const float* gn_l = gn + layer * D;
        const float* bn_l = bn + layer * D;
        const float* ge_l = ge + layer * DE;
        const float* be_l = be + layer * DE;

        qkv_kernel<<<NN / 16, dim3(64, 4), 0, stream>>>(h, Wq_l, Wk_l, Wv_l, q, kv);
        attn_kernel<<<NN / 4, dim3(64, 4), 0, stream>>>(q, kv, ebias_s, sorted_src,
                                                        offsets, agg);
        node_update_kernel<<<NN / 16, dim3(64, 4), 0, stream>>>(h, agg, Wo_l,
                                                                gn_l, bn_l, hb);
        // e after the last layer never affects h -> skip final edge update
        if (layer < L - 1) {
            const float* We_next = We + (layer + 1) * DE * H;
            edge_update_mfma_kernel<<<NE / 64, 256, 0, stream>>>(hb, eb_s, sorted_src,
                                                                 sorted_dst, Wt_l,
                                                                 bem_l, ge_l, be_l,
                                                                 We_next, ebias_s);
        }
    }
}